// Round 3
// baseline (1785.811 us; speedup 1.0000x reference)
//
#include <hip/hip_runtime.h>
#include <math.h>

#define NB 2
#define TSTEPS 288
#define NN 1024
#define DD 64
#define BT (NB*TSTEPS)          // 576
#define ROWS (BT*NN)            // 589824
#define OUT_HALF (ROWS*DD)      // 37748736

// workspace float offsets
#define OFF_DIS   0
#define OFF_VA    1024
#define OFF_VB    2048
#define OFF_SCAL  3072
#define OFF_BAR   3104
#define OFF_WTH1  3328
#define OFF_BTH1  3520
#define OFF_W02   3584
#define OFF_B02   3776
#define OFF_WTH2  3840
#define OFF_BTH2  4032
#define OFF_TEMP  4096
#define OFF_PE    22528
#define OFF_LP    40960
#define OFF_L2    1089536        // 40960 + 1024*1024
#define OFF_AIMG  2138112        // byte-region: 8 MB bf16 tile image

#define LAP_NB 128

typedef short bf16x8 __attribute__((ext_vector_type(8)));
typedef float f32x4  __attribute__((ext_vector_type(4)));

__device__ __forceinline__ unsigned rotl32(unsigned x, int n) {
  return (x << n) | (x >> (32 - n));
}

__device__ __forceinline__ unsigned short f2bf_rne(float v) {
  unsigned u = __float_as_uint(v);
  unsigned r = (u + 0x7FFFu + ((u >> 16) & 1u)) >> 16;
  return (unsigned short)r;
}
__device__ __forceinline__ float bf2f(unsigned short h) {
  return __uint_as_float(((unsigned)h) << 16);
}

__device__ __forceinline__ void glds16(const void* g, void* l) {
  __builtin_amdgcn_global_load_lds(
      (const __attribute__((address_space(1))) unsigned int*)g,
      (__attribute__((address_space(3))) unsigned int*)l, 16, 0, 0);
}

// device-scope grid barrier (LAP_NB blocks co-resident; 128 <= 256 CUs)
__device__ __forceinline__ void gbar(unsigned* cnt, unsigned* gen) {
  __syncthreads();
  __threadfence();
  if (threadIdx.x == 0) {
    unsigned g = __hip_atomic_load(gen, __ATOMIC_RELAXED, __HIP_MEMORY_SCOPE_AGENT);
    if (__hip_atomic_fetch_add(cnt, 1u, __ATOMIC_ACQ_REL, __HIP_MEMORY_SCOPE_AGENT)
        == LAP_NB - 1) {
      __hip_atomic_store(cnt, 0u, __ATOMIC_RELAXED, __HIP_MEMORY_SCOPE_AGENT);
      __hip_atomic_fetch_add(gen, 1u, __ATOMIC_ACQ_REL, __HIP_MEMORY_SCOPE_AGENT);
    } else {
      while (__hip_atomic_load(gen, __ATOMIC_ACQUIRE, __HIP_MEMORY_SCOPE_AGENT) == g)
        __builtin_amdgcn_s_sleep(2);
    }
  }
  __syncthreads();
  __threadfence();
}

// JAX threefry bits -> uniform(-1+eps,1) -> sqrt(2)*erfinv (XLA f32 polynomial)
__device__ __forceinline__ float bits_to_normal(unsigned bits) {
  float f = __uint_as_float((bits >> 9) | 0x3f800000u) - 1.0f;  // [0,1)
  const float lo = -0.99999994f;                                 // nextafter(-1,0)
  float u = f * 2.0f + lo;
  u = fmaxf(u, lo);
  float w = -log1pf(-u * u);
  float p;
  if (w < 5.0f) {
    w -= 2.5f;
    p = 2.81022636e-08f;
    p = fmaf(p, w, 3.43273939e-07f);
    p = fmaf(p, w, -3.5233877e-06f);
    p = fmaf(p, w, -4.39150654e-06f);
    p = fmaf(p, w, 0.00021858087f);
    p = fmaf(p, w, -0.00125372503f);
    p = fmaf(p, w, -0.00417768164f);
    p = fmaf(p, w, 0.246640727f);
    p = fmaf(p, w, 1.50140941f);
  } else {
    w = sqrtf(w) - 3.0f;
    p = -0.000200214257f;
    p = fmaf(p, w, 0.000100950558f);
    p = fmaf(p, w, 0.00134934322f);
    p = fmaf(p, w, -0.00367342844f);
    p = fmaf(p, w, 0.00573950773f);
    p = fmaf(p, w, -0.0076224613f);
    p = fmaf(p, w, 0.00943887047f);
    p = fmaf(p, w, 1.00167406f);
    p = fmaf(p, w, 2.83297682f);
  }
  return 1.41421356237309515f * (p * u);
}

__device__ __forceinline__ void threefry_pair(int i, float* v) {
  const unsigned k0 = 0u, k1 = 42u;
  const unsigned k2 = 0x1BD11BDAu ^ k0 ^ k1;
  unsigned x0 = (unsigned)i + k0;
  unsigned x1 = (unsigned)(i + 512) + k1;
#define TF_RND(r) { x0 += x1; x1 = rotl32(x1, r); x1 ^= x0; }
  TF_RND(13) TF_RND(15) TF_RND(26) TF_RND(6)
  x0 += k1; x1 += k2 + 1u;
  TF_RND(17) TF_RND(29) TF_RND(16) TF_RND(24)
  x0 += k2; x1 += k0 + 2u;
  TF_RND(13) TF_RND(15) TF_RND(26) TF_RND(6)
  x0 += k0; x1 += k1 + 3u;
  TF_RND(17) TF_RND(29) TF_RND(16) TF_RND(24)
  x0 += k1; x1 += k2 + 4u;
  TF_RND(13) TF_RND(15) TF_RND(26) TF_RND(6)
  x0 += k2; x1 += k0 + 5u;
#undef TF_RND
  v[i] = bits_to_normal(x0);
  v[i + 512] = bits_to_normal(x1);
}

// Fused tilde-Laplacian pipeline: rowsum -> initv -> 21x matvec -> lambda -> Lp
__global__ __launch_bounds__(256) void k_lap(const float* __restrict__ A,
                                             float* __restrict__ ws,
                                             unsigned* __restrict__ bar) {
  const int blk = blockIdx.x;   // 0..127
  const int t = threadIdx.x;
  const int lane = t & 63, w = t >> 6;
  float* dis = ws + OFF_DIS;
  float* va = ws + OFF_VA;
  float* vb = ws + OFF_VB;
  __shared__ float u[NN];
  __shared__ float r0[256], r1[256];
  // phase 1: rowsum -> dis
  for (int r = w; r < 8; r += 4) {
    int row = blk * 8 + r;
    const float* Ar = A + (size_t)row * NN;
    float sm = 0.f;
    for (int j = lane; j < NN; j += 64) sm += Ar[j];
    for (int off = 32; off > 0; off >>= 1) sm += __shfl_down(sm, off, 64);
    if (lane == 0) dis[row] = 1.0f / sqrtf(sm + 1e-12f);
  }
  // phase 1b: initv (block 0)
  if (blk == 0) {
    threefry_pair(t, va);
    threefry_pair(t + 256, va);
  }
  gbar(bar, bar + 1);
  // phase 2: 21 matvec iters (20 power steps + 1 for Rayleigh numerator)
  for (int it = 0; it < 21; ++it) {
    const float* vin = (it & 1) ? vb : va;
    float* vout = (it & 1) ? va : vb;
    for (int j = t; j < NN; j += 256) u[j] = dis[j] * vin[j];
    __syncthreads();
    for (int r = w; r < 8; r += 4) {
      int row = blk * 8 + r;
      const float* Ar = A + (size_t)row * NN;
      float sm = 0.f;
      for (int j = lane; j < NN; j += 64) sm += Ar[j] * u[j];
      for (int off = 32; off > 0; off >>= 1) sm += __shfl_down(sm, off, 64);
      if (lane == 0) vout[row] = vin[row] - dis[row] * sm;
    }
    gbar(bar, bar + 1);
  }
  // phase 3: lambda (block 0); va = v20, vb = v21
  if (blk == 0) {
    float d0 = 0.f, d1 = 0.f;
    for (int j = t; j < NN; j += 256) { float a = va[j]; d0 += a * a; d1 += a * vb[j]; }
    r0[t] = d0; r1[t] = d1;
    __syncthreads();
    for (int st = 128; st > 0; st >>= 1) {
      if (t < st) { r0[t] += r0[t + st]; r1[t] += r1[t + st]; }
      __syncthreads();
    }
    if (t == 0) {
      float lam = r1[0] / r0[0];
      lam = fminf(fmaxf(lam, 1e-6f), 2.0f);
      ws[OFF_SCAL] = 2.0f / lam;
    }
  }
  gbar(bar, bar + 1);
  // phase 4: build Lp
  float s = ws[OFF_SCAL];
  float* Lp = ws + OFF_LP;
  for (int r = 0; r < 8; ++r) {
    int row = blk * 8 + r;
    float di = dis[row];
    for (int j = t; j < NN; j += 256) {
      float m = (di * A[(size_t)row * NN + j]) * dis[j];
      float e = (j == row) ? 1.0f : 0.0f;
      Lp[(size_t)row * NN + j] = s * (e - m) - e;
    }
  }
}

// L2 = Lp @ Lp, fp32 tiled 64x64, thread 4x4
__global__ __launch_bounds__(256) void k_l2(const float* __restrict__ A, float* __restrict__ C) {
  __shared__ float sa[64][34];
  __shared__ float sb[32][64];
  int t = threadIdx.x;
  int bx = blockIdx.x & 15, by = blockIdx.x >> 4;
  int r0 = by * 64, c0 = bx * 64;
  int tx = t & 15, ty = t >> 4;
  float acc[4][4] = {};
  for (int k0 = 0; k0 < 1024; k0 += 32) {
    {
      int row = t >> 2, kc = (t & 3) * 8;
      const float* g = A + (size_t)(r0 + row) * 1024 + k0 + kc;
      float4 va = *(const float4*)g;
      float4 vb = *(const float4*)(g + 4);
      sa[row][kc + 0] = va.x; sa[row][kc + 1] = va.y; sa[row][kc + 2] = va.z; sa[row][kc + 3] = va.w;
      sa[row][kc + 4] = vb.x; sa[row][kc + 5] = vb.y; sa[row][kc + 6] = vb.z; sa[row][kc + 7] = vb.w;
      int kr = t >> 3, cc = (t & 7) * 8;
      const float* gb = A + (size_t)(k0 + kr) * 1024 + c0 + cc;
      *(float4*)&sb[kr][cc] = *(const float4*)gb;
      *(float4*)&sb[kr][cc + 4] = *(const float4*)(gb + 4);
    }
    __syncthreads();
#pragma unroll 8
    for (int kk = 0; kk < 32; ++kk) {
      float4 bv = *(const float4*)&sb[kk][tx * 4];
#pragma unroll
      for (int i = 0; i < 4; ++i) {
        float a = sa[ty * 4 + i][kk];
        acc[i][0] = fmaf(a, bv.x, acc[i][0]);
        acc[i][1] = fmaf(a, bv.y, acc[i][1]);
        acc[i][2] = fmaf(a, bv.z, acc[i][2]);
        acc[i][3] = fmaf(a, bv.w, acc[i][3]);
      }
    }
    __syncthreads();
  }
#pragma unroll
  for (int i = 0; i < 4; ++i) {
    float4 o; o.x = acc[i][0]; o.y = acc[i][1]; o.z = acc[i][2]; o.w = acc[i][3];
    *(float4*)&C[(size_t)(r0 + ty * 4 + i) * 1024 + c0 + tx * 4] = o;
  }
}

// Build swizzled bf16 hi/lo tile image of A_wide = [Lp | L2].
// Image layout: [rb 0..3][ks 0..63][256 rows x 128B], row = 64B hi + 64B lo,
// 16B chunks XOR-swizzled by ((row&7)<<4).
__global__ void k_split(const float* __restrict__ Lp, const float* __restrict__ L2,
                        unsigned char* __restrict__ Aimg) {
  int g = blockIdx.x * 256 + threadIdx.x;   // 0..262143
  int row = g >> 8;
  int oct = g & 255;
  int k0 = oct * 8;
  const float* src = (k0 < 1024) ? (Lp + (size_t)row * 1024 + k0)
                                 : (L2 + (size_t)row * 1024 + (k0 - 1024));
  bf16x8 hv, lv;
#pragma unroll
  for (int i = 0; i < 8; ++i) {
    float v = src[i];
    unsigned short h = f2bf_rne(v);
    hv[i] = (short)h;
    lv[i] = (short)f2bf_rne(v - bf2f(h));
  }
  int rb = row >> 8, r = row & 255;
  int ks = k0 >> 5, chunk = (k0 >> 3) & 3;
  int swz = (r & 7) << 4;
  size_t tile = ((size_t)(rb * 64 + ks)) * 32768;
  *(bf16x8*)(Aimg + tile + r * 128 + ((chunk * 16) ^ swz)) = hv;
  *(bf16x8*)(Aimg + tile + r * 128 + ((64 + chunk * 16) ^ swz)) = lv;
}

__global__ void k_temporal(const float* __restrict__ emb_day, const float* __restrict__ emb_week,
                           const int* __restrict__ midx, const int* __restrict__ widx,
                           float* __restrict__ temp, float* __restrict__ pe) {
  int tstep = blockIdx.x, d = threadIdx.x;
  int half = d >> 1;
  float dv = expf((float)(2 * half) * (-0.14391156831212787f));
  float ang = (float)tstep * dv;
  float p = (d & 1) ? cosf(ang) : sinf(ang);
  int mi = midx[tstep] % TSTEPS; if (mi < 0) mi += TSTEPS;
  int wi = widx[tstep] % 7;      if (wi < 0) wi += 7;
  float tv = (emb_day[mi * DD + d] + emb_week[wi * DD + d]) + p;
  temp[tstep * DD + d] = tv;
  pe[tstep * DD + d] = p;
}

// WB1 = W_in@th1, bB1 = b_in@th1, W02 = W_in@(th0-th2), b02 likewise,
// WB2 = 2*W_in@th2, bB2 = 2*b_in@th2
__global__ void k_smallmats(const float* __restrict__ W_in, const float* __restrict__ b_in,
                            const float* __restrict__ theta, float* __restrict__ ws) {
  int d = threadIdx.x;  // 0..63
  const float* th0 = theta;
  const float* th1 = theta + DD * DD;
  const float* th2 = theta + 2 * DD * DD;
  for (int c = 0; c < 3; ++c) {
    float s1 = 0.f, s02 = 0.f, s2 = 0.f;
    for (int k = 0; k < DD; ++k) {
      float wv = W_in[c * DD + k];
      s1 = fmaf(wv, th1[k * DD + d], s1);
      s02 = fmaf(wv, th0[k * DD + d] - th2[k * DD + d], s02);
      s2 = fmaf(2.0f * wv, th2[k * DD + d], s2);
    }
    ws[OFF_WTH1 + c * DD + d] = s1;
    ws[OFF_W02 + c * DD + d] = s02;
    ws[OFF_WTH2 + c * DD + d] = s2;
  }
  float s1 = 0.f, s02 = 0.f, s2 = 0.f;
  for (int k = 0; k < DD; ++k) {
    float bv = b_in[k];
    s1 = fmaf(bv, th1[k * DD + d], s1);
    s02 = fmaf(bv, th0[k * DD + d] - th2[k * DD + d], s02);
    s2 = fmaf(2.0f * bv, th2[k * DD + d], s2);
  }
  ws[OFF_BTH1 + d] = s1;
  ws[OFF_B02 + d] = s02;
  ws[OFF_BTH2 + d] = s2;
}

// V = [Lp | L2] @ [Xp@th1 ; 2*Xp@th2] with fused LN epilogue.
// 768 thr = 12 waves (wr = w&3 row-wave, wc = w>>2 bt-of-triple).
// Block tile: 256 rows x 3 bt (192 cols). Wave tile 64x64. dbuf sA 64KB.
// B-fragments produced IN-REGISTER from X (lane-local, no LDS). One barrier/K-step.
__global__ __launch_bounds__(768, 3) void k_gemm_mfma(
    const float* __restrict__ X, const unsigned char* __restrict__ Aimg,
    const float* __restrict__ ws, const float* __restrict__ cheb_bias,
    const float* __restrict__ ln_g, const float* __restrict__ ln_b,
    const float* __restrict__ W_in, const float* __restrict__ b_in,
    float* __restrict__ out_te, float* __restrict__ out_sp) {
  __shared__ __align__(16) unsigned char sA[2][32768];
  const int gb = blockIdx.x;            // 0..767
  const int x = gb & 7;                 // XCD pin
  const int rb = x & 3;                 // 256-row block of A
  const int btt = (x >> 2) * 96 + (gb >> 3);   // 0..191
  const int bt0 = btt * 3;
  const int t = threadIdx.x;
  const int lane = t & 63;
  const int w = t >> 6;                 // 0..11
  const int wr = w & 3;
  const int wc = w >> 2;                // 0..2
  const int bt = bt0 + wc;
  const int colq = lane & 15;
  const int kq = lane >> 4;             // 0..3
  const int off_hl = (kq * 16) ^ ((lane & 7) << 4);

  f32x4 acc[4][4];
#pragma unroll
  for (int mf = 0; mf < 4; ++mf)
#pragma unroll
    for (int nf = 0; nf < 4; ++nf) {
      acc[mf][nf][0] = 0.f; acc[mf][nf][1] = 0.f;
      acc[mf][nf][2] = 0.f; acc[mf][nf][3] = 0.f;
    }

  const unsigned char* tileB = Aimg + (size_t)rb * 64 * 32768;
  // prologue: stage ks=0 into sA[0]
  glds16(tileB + (size_t)t * 16, &sA[0][t * 16]);
  glds16(tileB + (size_t)(t + 768) * 16, &sA[0][(t + 768) * 16]);
  if (t < 512) glds16(tileB + (size_t)(t + 1536) * 16, &sA[0][(t + 1536) * 16]);
  __syncthreads();

  int buf = 0;
#pragma unroll 1
  for (int half = 0; half < 2; ++half) {
    // producer weights for this half (col = nf*16 + colq)
    const float* WB = ws + (half ? OFF_WTH2 : OFF_WTH1);
    const float* BB = ws + (half ? OFF_BTH2 : OFF_BTH1);
    float pw0[4], pw1[4], pw2[4], pbb[4];
#pragma unroll
    for (int nf = 0; nf < 4; ++nf) {
      int c = nf * 16 + colq;
      pw0[nf] = WB[c]; pw1[nf] = WB[64 + c]; pw2[nf] = WB[128 + c]; pbb[nf] = BB[c];
    }
#pragma unroll 1
    for (int k2 = 0; k2 < 32; ++k2) {
      const int ks = half * 32 + k2;
      // A frags from current buffer
      bf16x8 Ah[4], Al[4];
#pragma unroll
      for (int mf = 0; mf < 4; ++mf) {
        const unsigned char* ab = &sA[buf][(wr * 64 + mf * 16 + colq) * 128];
        Ah[mf] = *(const bf16x8*)(ab + off_hl);
        Al[mf] = *(const bf16x8*)(ab + (off_hl ^ 64));
      }
      // prefetch next K-step into other buffer
      if (ks < 63) {
        const unsigned char* g = tileB + (size_t)(ks + 1) * 32768;
        unsigned char* d = &sA[buf ^ 1][0];
        glds16(g + (size_t)t * 16, d + t * 16);
        glds16(g + (size_t)(t + 768) * 16, d + (t + 768) * 16);
        if (t < 512) glds16(g + (size_t)(t + 1536) * 16, d + (t + 1536) * 16);
      }
      // X rows for this lane's k-slots (wave: 4 distinct row-groups)
      const float* xb = X + ((size_t)bt * 1024 + (size_t)k2 * 32 + kq * 8) * 3;
      float4 q[6];
#pragma unroll
      for (int c6 = 0; c6 < 6; ++c6) q[c6] = *(const float4*)(xb + 4 * c6);
      float xv[24];
#pragma unroll
      for (int c6 = 0; c6 < 6; ++c6) {
        xv[4 * c6 + 0] = q[c6].x; xv[4 * c6 + 1] = q[c6].y;
        xv[4 * c6 + 2] = q[c6].z; xv[4 * c6 + 3] = q[c6].w;
      }
      // per nf: produce B frag in-register (truncation hi/lo split), then MFMA
#pragma unroll
      for (int nf = 0; nf < 4; ++nf) {
        bf16x8 Bh, Bl;
#pragma unroll
        for (int i = 0; i < 8; ++i) {
          float v = fmaf(xv[3 * i + 2], pw2[nf],
                    fmaf(xv[3 * i + 1], pw1[nf],
                    fmaf(xv[3 * i + 0], pw0[nf], pbb[nf])));
          unsigned u = __float_as_uint(v);
          Bh[i] = (short)(u >> 16);
          float lo = v - __uint_as_float(u & 0xFFFF0000u);
          Bl[i] = (short)(__float_as_uint(lo) >> 16);
        }
        __builtin_amdgcn_s_setprio(1);
#pragma unroll
        for (int mf = 0; mf < 4; ++mf) {
          acc[mf][nf] = __builtin_amdgcn_mfma_f32_16x16x32_bf16(Ah[mf], Bh, acc[mf][nf], 0, 0, 0);
          acc[mf][nf] = __builtin_amdgcn_mfma_f32_16x16x32_bf16(Ah[mf], Bl, acc[mf][nf], 0, 0, 0);
          acc[mf][nf] = __builtin_amdgcn_mfma_f32_16x16x32_bf16(Al[mf], Bh, acc[mf][nf], 0, 0, 0);
        }
        __builtin_amdgcn_s_setprio(0);
      }
      __syncthreads();   // compiler drains vmcnt+lgkm here; staged tile ready
      buf ^= 1;
    }
  }

  // ---- fused epilogue: X_te = LN(Xp+temp), X_sp = LN(Xp + Es + pe) ----
  const int tt = bt % TSTEPS;
  float ew0[4], ew1[4], ew2[4], eb[4];
  float f0[4], f1[4], f2[4], fb[4];
  float cb[4], gg[4], gbeta[4], tmv[4], pev[4];
#pragma unroll
  for (int nf = 0; nf < 4; ++nf) {
    int c = nf * 16 + colq;
    ew0[nf] = W_in[c]; ew1[nf] = W_in[64 + c]; ew2[nf] = W_in[128 + c]; eb[nf] = b_in[c];
    f0[nf] = ws[OFF_W02 + c]; f1[nf] = ws[OFF_W02 + 64 + c]; f2[nf] = ws[OFF_W02 + 128 + c];
    fb[nf] = ws[OFF_B02 + c];
    cb[nf] = cheb_bias[c]; gg[nf] = ln_g[c]; gbeta[nf] = ln_b[c];
    tmv[nf] = ws[OFF_TEMP + tt * DD + c];
    pev[nf] = ws[OFF_PE + tt * DD + c];
  }
#pragma unroll
  for (int mf = 0; mf < 4; ++mf) {
#pragma unroll
    for (int i = 0; i < 4; ++i) {
      int node = rb * 256 + wr * 64 + mf * 16 + kq * 4 + i;
      size_t rfl = (size_t)bt * 1024 + node;
      const float* xr = X + rfl * 3;
      float x0 = xr[0], x1 = xr[1], x2 = xr[2];
      float te[4], sp[4];
      float ste = 0.f, ssp = 0.f;
#pragma unroll
      for (int nf = 0; nf < 4; ++nf) {
        float xp = fmaf(x2, ew2[nf], fmaf(x1, ew1[nf], fmaf(x0, ew0[nf], eb[nf])));
        float x02 = fmaf(x2, f2[nf], fmaf(x1, f1[nf], fmaf(x0, f0[nf], fb[nf])));
        te[nf] = xp + tmv[nf];
        sp[nf] = xp + x02 + acc[mf][nf][i] + cb[nf] + pev[nf];
        ste += te[nf]; ssp += sp[nf];
      }
#pragma unroll
      for (int off = 1; off < 16; off <<= 1) {
        ste += __shfl_xor(ste, off, 64);
        ssp += __shfl_xor(ssp, off, 64);
      }
      float mte = ste * (1.0f / 64.0f), msp = ssp * (1.0f / 64.0f);
      float qte = 0.f, qsp = 0.f;
#pragma unroll
      for (int nf = 0; nf < 4; ++nf) {
        te[nf] -= mte; qte = fmaf(te[nf], te[nf], qte);
        sp[nf] -= msp; qsp = fmaf(sp[nf], sp[nf], qsp);
      }
#pragma unroll
      for (int off = 1; off < 16; off <<= 1) {
        qte += __shfl_xor(qte, off, 64);
        qsp += __shfl_xor(qsp, off, 64);
      }
      float rte = 1.0f / sqrtf(qte * (1.0f / 64.0f) + 1e-5f);
      float rsp = 1.0f / sqrtf(qsp * (1.0f / 64.0f) + 1e-5f);
      size_t ob = rfl * DD + colq;
#pragma unroll
      for (int nf = 0; nf < 4; ++nf) {
        out_te[ob + nf * 16] = te[nf] * rte * gg[nf] + gbeta[nf];
        out_sp[ob + nf * 16] = sp[nf] * rsp * gg[nf] + gbeta[nf];
      }
    }
  }
}

extern "C" void kernel_launch(void* const* d_in, const int* in_sizes, int n_in,
                              void* d_out, int out_size, void* d_ws, size_t ws_size,
                              hipStream_t stream) {
  (void)in_sizes; (void)n_in; (void)out_size; (void)ws_size;
  const float* X         = (const float*)d_in[0];
  const float* A         = (const float*)d_in[1];
  const float* W_in      = (const float*)d_in[2];
  const float* b_in      = (const float*)d_in[3];
  const float* theta     = (const float*)d_in[4];
  const float* cheb_bias = (const float*)d_in[5];
  const float* emb_day   = (const float*)d_in[6];
  const float* emb_week  = (const float*)d_in[7];
  const float* ln_g      = (const float*)d_in[8];
  const float* ln_b      = (const float*)d_in[9];
  const int*   midx      = (const int*)d_in[10];
  const int*   widx      = (const int*)d_in[11];
  float* out_te = (float*)d_out;
  float* out_sp = (float*)d_out + OUT_HALF;
  float* ws = (float*)d_ws;
  unsigned char* Aimg = (unsigned char*)(ws + OFF_AIMG);

  hipMemsetAsync((void*)(ws + OFF_BAR), 0, 8, stream);
  k_lap<<<LAP_NB, 256, 0, stream>>>(A, ws, (unsigned*)(ws + OFF_BAR));
  k_l2<<<256, 256, 0, stream>>>(ws + OFF_LP, ws + OFF_L2);
  k_split<<<1024, 256, 0, stream>>>(ws + OFF_LP, ws + OFF_L2, Aimg);
  k_smallmats<<<1, 64, 0, stream>>>(W_in, b_in, theta, ws);
  k_temporal<<<TSTEPS, 64, 0, stream>>>(emb_day, emb_week, midx, widx,
                                        ws + OFF_TEMP, ws + OFF_PE);
  k_gemm_mfma<<<768, 768, 0, stream>>>(X, Aimg, ws, cheb_bias, ln_g, ln_b,
                                       W_in, b_in, out_te, out_sp);
}

// Round 4
// 1019.421 us; speedup vs baseline: 1.7518x; 1.7518x over previous
//
#include <hip/hip_runtime.h>
#include <math.h>

#define NB 2
#define TSTEPS 288
#define NN 1024
#define DD 64
#define BT (NB*TSTEPS)          // 576
#define ROWS (BT*NN)            // 589824
#define OUT_HALF (ROWS*DD)      // 37748736

// workspace float offsets
#define OFF_DIS   0
#define OFF_VA    1024
#define OFF_VB    2048
#define OFF_SCAL  3072
#define OFF_WTH1  3328
#define OFF_BTH1  3520
#define OFF_W02   3584
#define OFF_B02   3776
#define OFF_WTH2  3840
#define OFF_BTH2  4032
#define OFF_TEMP  4096
#define OFF_PE    22528
#define OFF_L2F   40960
// byte offset of Aimg (8 MB), right after float region (1089536 floats)
#define AIMG_B    4358144

typedef short bf16x8 __attribute__((ext_vector_type(8)));
typedef float f32x4  __attribute__((ext_vector_type(4)));

__device__ __forceinline__ unsigned rotl32(unsigned x, int n) {
  return (x << n) | (x >> (32 - n));
}
__device__ __forceinline__ unsigned short f2bf_rne(float v) {
  unsigned u = __float_as_uint(v);
  unsigned r = (u + 0x7FFFu + ((u >> 16) & 1u)) >> 16;
  return (unsigned short)r;
}
__device__ __forceinline__ float bf2f(unsigned short h) {
  return __uint_as_float(((unsigned)h) << 16);
}
__device__ __forceinline__ void glds16(const void* g, void* l) {
  __builtin_amdgcn_global_load_lds(
      (const __attribute__((address_space(1))) unsigned int*)g,
      (__attribute__((address_space(3))) unsigned int*)l, 16, 0, 0);
}

// JAX threefry -> uniform -> sqrt(2)*erfinv (XLA f32 polynomial)
__device__ __forceinline__ float bits_to_normal(unsigned bits) {
  float f = __uint_as_float((bits >> 9) | 0x3f800000u) - 1.0f;
  const float lo = -0.99999994f;
  float u = f * 2.0f + lo;
  u = fmaxf(u, lo);
  float w = -log1pf(-u * u);
  float p;
  if (w < 5.0f) {
    w -= 2.5f;
    p = 2.81022636e-08f;
    p = fmaf(p, w, 3.43273939e-07f);
    p = fmaf(p, w, -3.5233877e-06f);
    p = fmaf(p, w, -4.39150654e-06f);
    p = fmaf(p, w, 0.00021858087f);
    p = fmaf(p, w, -0.00125372503f);
    p = fmaf(p, w, -0.00417768164f);
    p = fmaf(p, w, 0.246640727f);
    p = fmaf(p, w, 1.50140941f);
  } else {
    w = sqrtf(w) - 3.0f;
    p = -0.000200214257f;
    p = fmaf(p, w, 0.000100950558f);
    p = fmaf(p, w, 0.00134934322f);
    p = fmaf(p, w, -0.00367342844f);
    p = fmaf(p, w, 0.00573950773f);
    p = fmaf(p, w, -0.0076224613f);
    p = fmaf(p, w, 0.00943887047f);
    p = fmaf(p, w, 1.00167406f);
    p = fmaf(p, w, 2.83297682f);
  }
  return 1.41421356237309515f * (p * u);
}
__device__ __forceinline__ void threefry_pair(int i, float* v) {
  const unsigned k0 = 0u, k1 = 42u;
  const unsigned k2 = 0x1BD11BDAu ^ k0 ^ k1;
  unsigned x0 = (unsigned)i + k0;
  unsigned x1 = (unsigned)(i + 512) + k1;
#define TF_RND(r) { x0 += x1; x1 = rotl32(x1, r); x1 ^= x0; }
  TF_RND(13) TF_RND(15) TF_RND(26) TF_RND(6)
  x0 += k1; x1 += k2 + 1u;
  TF_RND(17) TF_RND(29) TF_RND(16) TF_RND(24)
  x0 += k2; x1 += k0 + 2u;
  TF_RND(13) TF_RND(15) TF_RND(26) TF_RND(6)
  x0 += k0; x1 += k1 + 3u;
  TF_RND(17) TF_RND(29) TF_RND(16) TF_RND(24)
  x0 += k1; x1 += k2 + 4u;
  TF_RND(13) TF_RND(15) TF_RND(26) TF_RND(6)
  x0 += k2; x1 += k0 + 5u;
#undef TF_RND
  v[i] = bits_to_normal(x0);
  v[i + 512] = bits_to_normal(x1);
}

// rowsum -> dis ; block 0 also writes v0 (threefry)
__global__ __launch_bounds__(256) void k_pre(const float* __restrict__ A,
                                             float* __restrict__ ws) {
  const int t = threadIdx.x, lane = t & 63, w = t >> 6;
  const int row = blockIdx.x * 4 + w;
  const float4* r4 = (const float4*)(A + (size_t)row * NN);
  float sm = 0.f;
#pragma unroll
  for (int q = 0; q < 4; ++q) {
    float4 a = r4[lane + 64 * q];
    sm += a.x + a.y + a.z + a.w;
  }
  for (int off = 32; off > 0; off >>= 1) sm += __shfl_down(sm, off, 64);
  if (lane == 0) ws[OFF_DIS + row] = 1.0f / sqrtf(sm + 1e-12f);
  if (blockIdx.x == 0) {
    threefry_pair(t, ws + OFF_VA);
    threefry_pair(t + 256, ws + OFF_VA);
  }
}

// L2F = L @ L via bf16 hi/lo x3 MFMA, L built on the fly from A,dis.
// Block 128x128, 256 thr, 4 waves (2x2), wave 64x64. K=1024, KT=32, dbuf.
__global__ __launch_bounds__(256) void k_sq(const float* __restrict__ A,
                                            const float* __restrict__ dis,
                                            float* __restrict__ C) {
  __shared__ __align__(16) unsigned char sA[2][16384];  // 128 r x 128 B
  __shared__ __align__(16) unsigned char sB[2][16384];  // 128 c x 128 B
  const int bx = blockIdx.x & 7, by = blockIdx.x >> 3;
  const int t = threadIdx.x, lane = t & 63, w = t >> 6;
  const int wr = w & 1, wc = w >> 1;
  const int cq = lane & 15, kq = lane >> 4;
  const int sl = t & 127, kgrp = t >> 7;        // staging: slot + k-group
  const float disr = dis[by * 128 + sl];
  const float disn = dis[bx * 128 + sl];
  f32x4 acc[4][4];
#pragma unroll
  for (int mf = 0; mf < 4; ++mf)
#pragma unroll
    for (int nf = 0; nf < 4; ++nf) { acc[mf][nf][0]=0.f; acc[mf][nf][1]=0.f; acc[mf][nf][2]=0.f; acc[mf][nf][3]=0.f; }

  for (int ks = -1; ks < 32; ++ks) {
    // stage ks+1 into buf (ks+1)&1
    if (ks < 31) {
      const int kn = ks + 1;
      const int buf = kn & 1;
      const int k0 = kn * 32 + kgrp * 16;
      // sA: rows by*128+sl, k k0..k0+15
      {
        const int gr = by * 128 + sl;
        const float* ar = A + (size_t)gr * NN + k0;
        bf16x8 h0, h1, l0, l1;
#pragma unroll
        for (int m = 0; m < 16; ++m) {
          float lval = ((gr == k0 + m) ? 1.0f : 0.0f) - disr * ar[m] * dis[k0 + m];
          unsigned short h = f2bf_rne(lval);
          unsigned short l = f2bf_rne(lval - bf2f(h));
          if (m < 8) { h0[m] = (short)h; l0[m] = (short)l; }
          else       { h1[m - 8] = (short)h; l1[m - 8] = (short)l; }
        }
        unsigned char* bbp = &sA[buf][sl * 128];
        const int swz = (sl & 7) << 4;
        *(bf16x8*)(bbp + ((kgrp * 32) ^ swz)) = h0;
        *(bf16x8*)(bbp + ((kgrp * 32 + 16) ^ swz)) = h1;
        *(bf16x8*)(bbp + ((64 + kgrp * 32) ^ swz)) = l0;
        *(bf16x8*)(bbp + ((64 + kgrp * 32 + 16) ^ swz)) = l1;
      }
      // sB: cols bx*128+sl, k k0..k0+15 (reads A columns, coalesced over sl)
      {
        const int gn = bx * 128 + sl;
        bf16x8 h0, h1, l0, l1;
#pragma unroll
        for (int m = 0; m < 16; ++m) {
          float lval = ((gn == k0 + m) ? 1.0f : 0.0f)
                     - dis[k0 + m] * A[(size_t)(k0 + m) * NN + gn] * disn;
          unsigned short h = f2bf_rne(lval);
          unsigned short l = f2bf_rne(lval - bf2f(h));
          if (m < 8) { h0[m] = (short)h; l0[m] = (short)l; }
          else       { h1[m - 8] = (short)h; l1[m - 8] = (short)l; }
        }
        unsigned char* bbp = &sB[buf][sl * 128];
        const int swz = (sl & 7) << 4;
        *(bf16x8*)(bbp + ((kgrp * 32) ^ swz)) = h0;
        *(bf16x8*)(bbp + ((kgrp * 32 + 16) ^ swz)) = h1;
        *(bf16x8*)(bbp + ((64 + kgrp * 32) ^ swz)) = l0;
        *(bf16x8*)(bbp + ((64 + kgrp * 32 + 16) ^ swz)) = l1;
      }
    }
    if (ks >= 0) {
      const int cur = ks & 1;
      bf16x8 Bh[4], Bl[4];
#pragma unroll
      for (int nf = 0; nf < 4; ++nf) {
        const int lc = wc * 64 + nf * 16 + cq;
        const unsigned char* bbp = &sB[cur][lc * 128];
        const int swz = (lc & 7) << 4;
        Bh[nf] = *(const bf16x8*)(bbp + ((kq * 16) ^ swz));
        Bl[nf] = *(const bf16x8*)(bbp + ((64 + kq * 16) ^ swz));
      }
#pragma unroll
      for (int mf = 0; mf < 4; ++mf) {
        const int lr = wr * 64 + mf * 16 + cq;
        const unsigned char* abp = &sA[cur][lr * 128];
        const int swz = (lr & 7) << 4;
        bf16x8 Ah = *(const bf16x8*)(abp + ((kq * 16) ^ swz));
        bf16x8 Al = *(const bf16x8*)(abp + ((64 + kq * 16) ^ swz));
#pragma unroll
        for (int nf = 0; nf < 4; ++nf) {
          acc[mf][nf] = __builtin_amdgcn_mfma_f32_16x16x32_bf16(Ah, Bh[nf], acc[mf][nf], 0, 0, 0);
          acc[mf][nf] = __builtin_amdgcn_mfma_f32_16x16x32_bf16(Ah, Bl[nf], acc[mf][nf], 0, 0, 0);
          acc[mf][nf] = __builtin_amdgcn_mfma_f32_16x16x32_bf16(Al, Bh[nf], acc[mf][nf], 0, 0, 0);
        }
      }
    }
    __syncthreads();
  }
#pragma unroll
  for (int mf = 0; mf < 4; ++mf)
#pragma unroll
    for (int i = 0; i < 4; ++i) {
      const int gr = by * 128 + wr * 64 + mf * 16 + kq * 4 + i;
#pragma unroll
      for (int nf = 0; nf < 4; ++nf) {
        const int gc = bx * 128 + wc * 64 + nf * 16 + cq;
        C[(size_t)gr * NN + gc] = acc[mf][nf][i];
      }
    }
}

// y = L2F @ v   (fp32, 4 rows per block)
__global__ __launch_bounds__(256) void k_mv(const float* __restrict__ M,
                                            const float* __restrict__ vin,
                                            float* __restrict__ vout) {
  const int lane = threadIdx.x & 63, w = threadIdx.x >> 6;
  const int row = blockIdx.x * 4 + w;
  const float4* r4 = (const float4*)(M + (size_t)row * NN);
  const float4* v4 = (const float4*)vin;
  float sm = 0.f;
#pragma unroll
  for (int q = 0; q < 4; ++q) {
    float4 a = r4[lane + 64 * q], b = v4[lane + 64 * q];
    sm = fmaf(a.x, b.x, sm); sm = fmaf(a.y, b.y, sm);
    sm = fmaf(a.z, b.z, sm); sm = fmaf(a.w, b.w, sm);
  }
  for (int off = 32; off > 0; off >>= 1) sm += __shfl_down(sm, off, 64);
  if (lane == 0) vout[row] = sm;
}

// w = v - dis .* (A (dis .* v))   (one Rayleigh matvec on original L)
__global__ __launch_bounds__(256) void k_ray(const float* __restrict__ A,
                                             const float* __restrict__ dis,
                                             const float* __restrict__ vin,
                                             float* __restrict__ vout) {
  __shared__ float u[NN];
  const int t = threadIdx.x, lane = t & 63, w = t >> 6;
  for (int j = t; j < NN; j += 256) u[j] = dis[j] * vin[j];
  __syncthreads();
  const int row = blockIdx.x * 4 + w;
  const float4* r4 = (const float4*)(A + (size_t)row * NN);
  float sm = 0.f;
#pragma unroll
  for (int q = 0; q < 4; ++q) {
    float4 a = r4[lane + 64 * q];
    const int j = (lane + 64 * q) * 4;
    sm = fmaf(a.x, u[j], sm); sm = fmaf(a.y, u[j + 1], sm);
    sm = fmaf(a.z, u[j + 2], sm); sm = fmaf(a.w, u[j + 3], sm);
  }
  for (int off = 32; off > 0; off >>= 1) sm += __shfl_down(sm, off, 64);
  if (lane == 0) vout[row] = vin[row] - dis[row] * sm;
}

__global__ void k_lambda(const float* __restrict__ v20, const float* __restrict__ v21,
                         float* __restrict__ scal) {
  __shared__ float r0[256], r1[256];
  int t = threadIdx.x;
  float d0 = 0.f, d1 = 0.f;
  for (int j = t; j < NN; j += 256) { float a = v20[j]; d0 += a * a; d1 += a * v21[j]; }
  r0[t] = d0; r1[t] = d1;
  __syncthreads();
  for (int st = 128; st > 0; st >>= 1) {
    if (t < st) { r0[t] += r0[t + st]; r1[t] += r1[t + st]; }
    __syncthreads();
  }
  if (t == 0) {
    float lam = r1[0] / r0[0];
    lam = fminf(fmaxf(lam, 1e-6f), 2.0f);
    scal[0] = 2.0f / lam;
  }
}

// Aimg = hi/lo bf16 of [ s*L - I  |  s^2*L2 - 2s*L + I ], swizzled tiles
// [rb 0..3][ks 0..63][256 rows x 128 B]
__global__ void k_split(const float* __restrict__ A, const float* __restrict__ dis,
                        const float* __restrict__ scal, const float* __restrict__ L2,
                        unsigned char* __restrict__ Aimg) {
  const int g = blockIdx.x * 256 + threadIdx.x;   // 0..262143
  const int row = g >> 8, oct = g & 255, k0 = oct * 8;
  const int kk0 = k0 & 1023;
  const float s = scal[0], disr = dis[row];
  const float* ar = A + (size_t)row * NN + kk0;
  const float* l2r = L2 + (size_t)row * NN + kk0;
  bf16x8 hv, lv;
#pragma unroll
  for (int i = 0; i < 8; ++i) {
    float m = disr * ar[i] * dis[kk0 + i];
    float e = (row == kk0 + i) ? 1.0f : 0.0f;
    float lval = e - m;
    float v = (k0 < 1024) ? (s * lval - e)
                          : (s * s * l2r[i] - 2.0f * s * lval + e);
    unsigned short h = f2bf_rne(v);
    hv[i] = (short)h;
    lv[i] = (short)f2bf_rne(v - bf2f(h));
  }
  const int rb = row >> 8, r = row & 255;
  const int ks = k0 >> 5, chunk = (k0 >> 3) & 3;
  const int swz = (r & 7) << 4;
  size_t tile = ((size_t)(rb * 64 + ks)) * 32768;
  *(bf16x8*)(Aimg + tile + r * 128 + ((chunk * 16) ^ swz)) = hv;
  *(bf16x8*)(Aimg + tile + r * 128 + ((64 + chunk * 16) ^ swz)) = lv;
}

__global__ void k_temporal(const float* __restrict__ emb_day, const float* __restrict__ emb_week,
                           const int* __restrict__ midx, const int* __restrict__ widx,
                           float* __restrict__ temp, float* __restrict__ pe) {
  int tstep = blockIdx.x, d = threadIdx.x;
  int half = d >> 1;
  float dv = expf((float)(2 * half) * (-0.14391156831212787f));
  float ang = (float)tstep * dv;
  float p = (d & 1) ? cosf(ang) : sinf(ang);
  int mi = midx[tstep] % TSTEPS; if (mi < 0) mi += TSTEPS;
  int wi = widx[tstep] % 7;      if (wi < 0) wi += 7;
  float tv = (emb_day[mi * DD + d] + emb_week[wi * DD + d]) + p;
  temp[tstep * DD + d] = tv;
  pe[tstep * DD + d] = p;
}

__global__ void k_smallmats(const float* __restrict__ W_in, const float* __restrict__ b_in,
                            const float* __restrict__ theta, float* __restrict__ ws) {
  int d = threadIdx.x;  // 0..63
  const float* th0 = theta;
  const float* th1 = theta + DD * DD;
  const float* th2 = theta + 2 * DD * DD;
  for (int c = 0; c < 3; ++c) {
    float s1 = 0.f, s02 = 0.f, s2 = 0.f;
    for (int k = 0; k < DD; ++k) {
      float wv = W_in[c * DD + k];
      s1 = fmaf(wv, th1[k * DD + d], s1);
      s02 = fmaf(wv, th0[k * DD + d] - th2[k * DD + d], s02);
      s2 = fmaf(2.0f * wv, th2[k * DD + d], s2);
    }
    ws[OFF_WTH1 + c * DD + d] = s1;
    ws[OFF_W02 + c * DD + d] = s02;
    ws[OFF_WTH2 + c * DD + d] = s2;
  }
  float s1 = 0.f, s02 = 0.f, s2 = 0.f;
  for (int k = 0; k < DD; ++k) {
    float bv = b_in[k];
    s1 = fmaf(bv, th1[k * DD + d], s1);
    s02 = fmaf(bv, th0[k * DD + d] - th2[k * DD + d], s02);
    s2 = fmaf(2.0f * bv, th2[k * DD + d], s2);
  }
  ws[OFF_BTH1 + d] = s1;
  ws[OFF_B02 + d] = s02;
  ws[OFF_BTH2 + d] = s2;
}

// V = [Lp | Lp^2] @ [Xp@th1 ; 2*Xp@th2] -> out_sp (raw V)
// BM=256 rows, BN=192 (3 bt), 512 thr = 8 waves (2 wr x 4 wc), wave 128x48.
// Waves 0-5 produce B in-LDS from X (wave-uniform scalar X loads); waves 6-7
// stage A via global_load_lds from pre-swizzled Aimg. dbuf, 1 barrier/K-step.
__global__ __launch_bounds__(512, 2) void k_gemm_mfma(
    const float* __restrict__ X, const unsigned char* __restrict__ Aimg,
    const float* __restrict__ ws, float* __restrict__ out_sp) {
  __shared__ __align__(16) unsigned char sA[2][32768];  // 256 r x 128 B
  __shared__ __align__(16) unsigned char sB[2][24576];  // 192 c x 128 B
  const int gb = blockIdx.x;             // 0..767
  const int xcd = gb & 7;
  const int rb = xcd & 3;
  const int btg = (xcd >> 2) * 96 + (gb >> 3);   // 0..191
  const int bt0 = btg * 3;
  const int t = threadIdx.x;
  const int lane = t & 63;
  const int w = t >> 6;                  // 0..7
  const int wr = w >> 2, wc = w & 3;
  const int cq = lane & 15, kq = lane >> 4;
  const bool producer = (w < 6);
  const int pb = w >> 1;                 // producer bt-local (0..2)
  const int pkh = w & 1;                 // producer k-half (0/1)
  const int pc = pb * 64 + lane;         // producer col (0..191)
  // producer weights for this col (d = lane), both halves
  const float w1_0 = ws[OFF_WTH1 + lane], w1_1 = ws[OFF_WTH1 + 64 + lane],
              w1_2 = ws[OFF_WTH1 + 128 + lane], b1 = ws[OFF_BTH1 + lane];
  const float w2_0 = ws[OFF_WTH2 + lane], w2_1 = ws[OFF_WTH2 + 64 + lane],
              w2_2 = ws[OFF_WTH2 + 128 + lane], b2 = ws[OFF_BTH2 + lane];

  f32x4 acc[8][3];
#pragma unroll
  for (int mf = 0; mf < 8; ++mf)
#pragma unroll
    for (int nf = 0; nf < 3; ++nf) { acc[mf][nf][0]=0.f; acc[mf][nf][1]=0.f; acc[mf][nf][2]=0.f; acc[mf][nf][3]=0.f; }

  const unsigned char* tileB = Aimg + ((size_t)rb * 64) * 32768;
  const int t2 = t - 384;                // stager slot (waves 6,7): 0..127

  for (int ks = -1; ks < 64; ++ks) {
    if (ks < 63) {
      const int kn = ks + 1;
      const int buf = kn & 1;
      if (producer) {
        // produce B(kn) into sB[buf]
        const int half = (kn < 32) ? 0 : 1;
        const int j0 = ((half ? (kn - 32) : kn) << 5) + pkh * 16;
        const unsigned xoff = (unsigned)(bt0 + pb) * 1024u + (unsigned)j0;
        const int base4 = __builtin_amdgcn_readfirstlane((int)((xoff * 3u) >> 2));
        const float4* xq = (const float4*)X + base4;
        float4 q[12];
#pragma unroll
        for (int i = 0; i < 12; ++i) q[i] = xq[i];
        float sx[48];
#pragma unroll
        for (int i = 0; i < 12; ++i) {
          sx[4*i] = q[i].x; sx[4*i+1] = q[i].y; sx[4*i+2] = q[i].z; sx[4*i+3] = q[i].w;
        }
        const float pw0 = half ? w2_0 : w1_0;
        const float pw1 = half ? w2_1 : w1_1;
        const float pw2 = half ? w2_2 : w1_2;
        const float pbb = half ? b2 : b1;
        bf16x8 h0, h1, l0, l1;
#pragma unroll
        for (int m = 0; m < 16; ++m) {
          float v = fmaf(sx[3*m+2], pw2, fmaf(sx[3*m+1], pw1, fmaf(sx[3*m], pw0, pbb)));
          unsigned short h = f2bf_rne(v);
          unsigned short l = f2bf_rne(v - bf2f(h));
          if (m < 8) { h0[m] = (short)h; l0[m] = (short)l; }
          else       { h1[m-8] = (short)h; l1[m-8] = (short)l; }
        }
        unsigned char* bbp = &sB[buf][pc * 128];
        const int swz = (pc & 7) << 4;
        *(bf16x8*)(bbp + ((pkh * 32) ^ swz)) = h0;
        *(bf16x8*)(bbp + ((pkh * 32 + 16) ^ swz)) = h1;
        *(bf16x8*)(bbp + ((64 + pkh * 32) ^ swz)) = l0;
        *(bf16x8*)(bbp + ((64 + pkh * 32 + 16) ^ swz)) = l1;
      } else {
        // stage A(kn) into sA[buf] (32 KB, 128 lanes x 16 x 16B)
        const unsigned char* src = tileB + ((size_t)kn) * 32768 + (size_t)t2 * 16;
        unsigned char* dst = &sA[buf][t2 * 16];
#pragma unroll
        for (int i = 0; i < 16; ++i)
          glds16(src + i * 2048, dst + i * 2048);
      }
    }
    if (ks >= 0) {
      const int cur = ks & 1;
      bf16x8 Bh[3], Bl[3];
#pragma unroll
      for (int nf = 0; nf < 3; ++nf) {
        const int col = wc * 48 + nf * 16 + cq;
        const unsigned char* bbp = &sB[cur][col * 128];
        const int swz = (col & 7) << 4;
        Bh[nf] = *(const bf16x8*)(bbp + ((kq * 16) ^ swz));
        Bl[nf] = *(const bf16x8*)(bbp + ((64 + kq * 16) ^ swz));
      }
      __builtin_amdgcn_s_setprio(1);
#pragma unroll
      for (int mf = 0; mf < 8; ++mf) {
        const int r = wr * 128 + mf * 16 + cq;
        const unsigned char* abp = &sA[cur][r * 128];
        const int swz = (r & 7) << 4;
        bf16x8 Ah = *(const bf16x8*)(abp + ((kq * 16) ^ swz));
        bf16x8 Al = *(const bf16x8*)(abp + ((64 + kq * 16) ^ swz));
#pragma unroll
        for (int nf = 0; nf < 3; ++nf) {
          acc[mf][nf] = __builtin_amdgcn_mfma_f32_16x16x32_bf16(Ah, Bh[nf], acc[mf][nf], 0, 0, 0);
          acc[mf][nf] = __builtin_amdgcn_mfma_f32_16x16x32_bf16(Ah, Bl[nf], acc[mf][nf], 0, 0, 0);
          acc[mf][nf] = __builtin_amdgcn_mfma_f32_16x16x32_bf16(Al, Bh[nf], acc[mf][nf], 0, 0, 0);
        }
      }
      __builtin_amdgcn_s_setprio(0);
    }
    __syncthreads();
  }
  // store raw V
#pragma unroll
  for (int mf = 0; mf < 8; ++mf)
#pragma unroll
    for (int i = 0; i < 4; ++i) {
      const int node = rb * 256 + wr * 128 + mf * 16 + kq * 4 + i;
#pragma unroll
      for (int nf = 0; nf < 3; ++nf) {
        const int col = wc * 48 + nf * 16 + cq;   // 0..191
        const int bt = bt0 + (col >> 6);
        const int d = col & 63;
        out_sp[((size_t)bt * 1024 + node) * DD + d] = acc[mf][nf][i];
      }
    }
}

// X_te = LN(Xp + temp), X_sp = LN(Xp + (X@W02 + b02 + V + cheb_bias) + pe)
__global__ __launch_bounds__(256) void k_final(const float* __restrict__ X,
    const float* __restrict__ W_in, const float* __restrict__ b_in,
    const float* __restrict__ cheb_bias, const float* __restrict__ ln_g,
    const float* __restrict__ ln_b, const float* __restrict__ temp,
    const float* __restrict__ pe, const float* __restrict__ W02,
    const float* __restrict__ b02, float* __restrict__ out_te, float* out_sp) {
  const int t = threadIdx.x;
  const int lane = t & 63;
  const size_t row = (size_t)blockIdx.x * 4 + (t >> 6);
  const int tt = (int)((row >> 10) % TSTEPS);
  const float x0 = X[row * 3 + 0], x1 = X[row * 3 + 1], x2 = X[row * 3 + 2];
  float xp = x0 * W_in[lane];
  xp = fmaf(x1, W_in[DD + lane], xp);
  xp = fmaf(x2, W_in[2 * DD + lane], xp);
  xp += b_in[lane];
  float x02 = x0 * W02[lane];
  x02 = fmaf(x1, W02[DD + lane], x02);
  x02 = fmaf(x2, W02[2 * DD + lane], x02);
  x02 += b02[lane];
  const size_t o = row * DD + lane;
  const float v = out_sp[o];            // raw V
  const float es = (x02 + v) + cheb_bias[lane];
  const float g = ln_g[lane], bb = ln_b[lane];
  float a_te = xp + temp[tt * DD + lane];
  float a_sp = (xp + es) + pe[tt * DD + lane];
  float s = a_te;
  for (int off = 32; off > 0; off >>= 1) s += __shfl_xor(s, off, 64);
  float m = s * (1.0f / 64.0f);
  float dv = a_te - m;
  float q = dv * dv;
  for (int off = 32; off > 0; off >>= 1) q += __shfl_xor(q, off, 64);
  float var = q * (1.0f / 64.0f);
  out_te[o] = dv * (1.0f / sqrtf(var + 1e-5f)) * g + bb;
  s = a_sp;
  for (int off = 32; off > 0; off >>= 1) s += __shfl_xor(s, off, 64);
  m = s * (1.0f / 64.0f);
  dv = a_sp - m;
  q = dv * dv;
  for (int off = 32; off > 0; off >>= 1) q += __shfl_xor(q, off, 64);
  var = q * (1.0f / 64.0f);
  out_sp[o] = dv * (1.0f / sqrtf(var + 1e-5f)) * g + bb;
}

extern "C" void kernel_launch(void* const* d_in, const int* in_sizes, int n_in,
                              void* d_out, int out_size, void* d_ws, size_t ws_size,
                              hipStream_t stream) {
  (void)in_sizes; (void)n_in; (void)out_size; (void)ws_size;
  const float* X         = (const float*)d_in[0];
  const float* A         = (const float*)d_in[1];
  const float* W_in      = (const float*)d_in[2];
  const float* b_in      = (const float*)d_in[3];
  const float* theta     = (const float*)d_in[4];
  const float* cheb_bias = (const float*)d_in[5];
  const float* emb_day   = (const float*)d_in[6];
  const float* emb_week  = (const float*)d_in[7];
  const float* ln_g      = (const float*)d_in[8];
  const float* ln_b      = (const float*)d_in[9];
  const int*   midx      = (const int*)d_in[10];
  const int*   widx      = (const int*)d_in[11];
  float* out_te = (float*)d_out;
  float* out_sp = (float*)d_out + OUT_HALF;
  float* ws = (float*)d_ws;
  unsigned char* Aimg = (unsigned char*)d_ws + AIMG_B;

  k_pre<<<256, 256, 0, stream>>>(A, ws);
  k_sq<<<64, 256, 0, stream>>>(A, ws + OFF_DIS, ws + OFF_L2F);
  for (int it = 0; it < 10; ++it) {
    const float* vin = ws + ((it & 1) ? OFF_VB : OFF_VA);
    float* vout      = ws + ((it & 1) ? OFF_VA : OFF_VB);
    k_mv<<<256, 256, 0, stream>>>(ws + OFF_L2F, vin, vout);
  }
  k_ray<<<256, 256, 0, stream>>>(A, ws + OFF_DIS, ws + OFF_VA, ws + OFF_VB);
  k_lambda<<<1, 256, 0, stream>>>(ws + OFF_VA, ws + OFF_VB, ws + OFF_SCAL);
  k_smallmats<<<1, 64, 0, stream>>>(W_in, b_in, theta, ws);
  k_temporal<<<TSTEPS, 64, 0, stream>>>(emb_day, emb_week, midx, widx,
                                        ws + OFF_TEMP, ws + OFF_PE);
  k_split<<<1024, 256, 0, stream>>>(A, ws + OFF_DIS, ws + OFF_SCAL,
                                    ws + OFF_L2F, Aimg);
  k_gemm_mfma<<<768, 512, 0, stream>>>(X, Aimg, ws, out_sp);
  k_final<<<ROWS / 4, 256, 0, stream>>>(X, W_in, b_in, cheb_bias, ln_g, ln_b,
                                        ws + OFF_TEMP, ws + OFF_PE,
                                        ws + OFF_W02, ws + OFF_B02,
                                        out_te, out_sp);
}